// Round 1
// baseline (1019.537 us; speedup 1.0000x reference)
//
#include <hip/hip_runtime.h>
#include <cstdint>
#include <cstddef>

typedef unsigned short u16;
typedef __attribute__((ext_vector_type(8))) short short8;
typedef __attribute__((ext_vector_type(4))) float f32x4;

#define B_DIM 16
#define C_DIM 64
#define T_DIM 64
#define N_DIM 1024
#define KS_DIM 3

#define BN 128                    // n columns per workgroup
#define BK 32                     // K (m) step
#define NSTEP (N_DIM / BK)        // 32

__device__ __forceinline__ u16 f2bf(float f) {
  union { float f; uint32_t u; } v; v.f = f;
  uint32_t r = (v.u + 0x7FFFu + ((v.u >> 16) & 1u)) >> 16;  // RNE
  return (u16)r;
}

__device__ __forceinline__ void gload_lds16(const void* g, void* l) {
  __builtin_amdgcn_global_load_lds(
      (const __attribute__((address_space(1))) void*)g,
      (__attribute__((address_space(3))) void*)l, 16, 0, 0);
}

// ws kernel 1: Lk fp32 -> bf16 (natural [k][n][m] layout = B^T rows over m)
__global__ void k_convert_lk(const float* __restrict__ Lk, u16* __restrict__ Lkb) {
  size_t idx = (size_t)blockIdx.x * blockDim.x + threadIdx.x;  // one per 8 elems
  const float4* s = (const float4*)(Lk + idx * 8);
  float4 f0 = s[0], f1 = s[1];
  short8 h;
  h[0] = (short)f2bf(f0.x); h[1] = (short)f2bf(f0.y);
  h[2] = (short)f2bf(f0.z); h[3] = (short)f2bf(f0.w);
  h[4] = (short)f2bf(f1.x); h[5] = (short)f2bf(f1.y);
  h[6] = (short)f2bf(f1.z); h[7] = (short)f2bf(f1.w);
  *(short8*)(Lkb + idx * 8) = h;
}

// ws kernel 2: theta[i][o][k] -> thT[o][k*64+i] bf16 (A-operand for mix GEMM)
__global__ void k_convert_theta(const float* __restrict__ th, u16* __restrict__ thT) {
  int f = blockIdx.x * blockDim.x + threadIdx.x;
  if (f < C_DIM * C_DIM * KS_DIM) {
    int o = f / 192, ik = f % 192, k = ik >> 6, i = ik & 63;
    thT[f] = f2bf(th[(i * 64 + o) * 3 + k]);
  }
}

// Fused: z-GEMM (M=64 i, N=384 (k,n), K=1024 m) -> LDS transpose -> theta-mix
// MFMA (M=64 o, N=128 n, K=192 ik) -> bias + residual + relu.
__global__ __launch_bounds__(256, 3)
void k_main(const float* __restrict__ x, const u16* __restrict__ Lkb,
            const u16* __restrict__ thT, const float* __restrict__ bias,
            float* __restrict__ out) {
  __shared__ __align__(16) char smem[51200];
  u16* Ab = (u16*)smem;               // phase 1: [64][32] bf16 (4 KB)
  u16* Bb = (u16*)(smem + 4096);      // phase 1: [384][32] bf16 (24 KB)
  char* Zb = smem;                    // phase 2: zT [128][200] bf16 (50 KB)

  const int tid = threadIdx.x;
  const int wv = tid >> 6;
  const int ln = tid & 63;
  const int lg = ln >> 4;
  const int l16 = ln & 15;

  const int bid = blockIdx.x;
  const int nt = bid & 7;           // n-tile fast: 8 WGs share one x slice
  const int slice = bid >> 3;
  const int bb = slice >> 6;
  const int tti = slice & 63;

  const f32x4 vzero = {0.f, 0.f, 0.f, 0.f};
  f32x4 acc[4][6];
#pragma unroll
  for (int a = 0; a < 4; ++a)
#pragma unroll
    for (int c = 0; c < 6; ++c) acc[a][c] = vzero;

  const int arow = tid >> 2, am = tid & 3;
  const float* a_src = x + (((size_t)bb * C_DIM + arow) * T_DIM + tti) * N_DIM + am * 8;

  for (int kk = 0; kk < NSTEP; ++kk) {
    if (kk) __syncthreads();
    // stage A: x fp32 -> bf16 -> LDS [64][32]
    {
      const float4* s = (const float4*)(a_src + kk * BK);
      float4 f0 = s[0], f1 = s[1];
      short8 h;
      h[0] = (short)f2bf(f0.x); h[1] = (short)f2bf(f0.y);
      h[2] = (short)f2bf(f0.z); h[3] = (short)f2bf(f0.w);
      h[4] = (short)f2bf(f1.x); h[5] = (short)f2bf(f1.y);
      h[6] = (short)f2bf(f1.z); h[7] = (short)f2bf(f1.w);
      *(short8*)(Ab + arow * BK + am * 8) = h;
    }
    // stage B: Lkb rows (k, nt*128+nl) x m-slice via global_load_lds (16B/lane)
#pragma unroll
    for (int it = 0; it < 6; ++it) {
      int L = it * 256 + tid;              // 0..1535 -> 24 KB linear
      int brow = L >> 2, msub = L & 3;
      int k = brow >> 7, nl = brow & 127;
      const u16* src = Lkb + ((size_t)(k * N_DIM + nt * BN + nl)) * N_DIM + kk * BK + msub * 8;
      char* dst = (char*)Bb + (size_t)(it * 256 + wv * 64) * 16;  // wave-uniform base
      gload_lds16(src, dst);
    }
    __syncthreads();
    // compute: 24 MFMA per wave per K-step
    short8 af[4];
#pragma unroll
    for (int mi = 0; mi < 4; ++mi)
      af[mi] = *(const short8*)(Ab + (mi * 16 + l16) * BK + lg * 8);
#pragma unroll
    for (int ci = 0; ci < 6; ++ci) {
      int r = wv * 96 + ci * 16 + l16;
      short8 bf = *(const short8*)(Bb + r * BK + lg * 8);
#pragma unroll
      for (int mi = 0; mi < 4; ++mi)
        acc[mi][ci] = __builtin_amdgcn_mfma_f32_16x16x32_bf16(af[mi], bf, acc[mi][ci], 0, 0, 0);
    }
  }

  __syncthreads();
  // transpose z into LDS: zT[nl][k*64+i] (row padded to 200 bf16)
#pragma unroll
  for (int mi = 0; mi < 4; ++mi)
#pragma unroll
    for (int ci = 0; ci < 6; ++ci) {
      int c = wv * 96 + ci * 16 + l16;        // (k,nl) col of z
      int k = c >> 7, nl = c & 127;
      int ib = mi * 16 + lg * 4;              // i of reg 0
      uint32_t p0 = (uint32_t)f2bf(acc[mi][ci][0]) | ((uint32_t)f2bf(acc[mi][ci][1]) << 16);
      uint32_t p1 = (uint32_t)f2bf(acc[mi][ci][2]) | ((uint32_t)f2bf(acc[mi][ci][3]) << 16);
      *(uint32_t*)(Zb + ((size_t)nl * 200 + k * 64 + ib) * 2) = p0;
      *(uint32_t*)(Zb + ((size_t)nl * 200 + k * 64 + ib + 2) * 2) = p1;
    }
  __syncthreads();

  // mix GEMM: out[o][n] = sum_ik thT[o][ik] * zT[n][ik]
  f32x4 acc2[4][2];
#pragma unroll
  for (int a = 0; a < 4; ++a)
#pragma unroll
    for (int c = 0; c < 2; ++c) acc2[a][c] = vzero;

#pragma unroll
  for (int ks = 0; ks < 6; ++ks) {
    short8 af2[4];
#pragma unroll
    for (int mo = 0; mo < 4; ++mo) {
      int o = mo * 16 + l16;
      af2[mo] = *(const short8*)(thT + o * 192 + ks * 32 + lg * 8);  // L2-hot
    }
#pragma unroll
    for (int cj = 0; cj < 2; ++cj) {
      int nl = wv * 32 + cj * 16 + l16;
      short8 bf = *(const short8*)(Zb + ((size_t)nl * 200 + ks * 32 + lg * 8) * 2);
#pragma unroll
      for (int mo = 0; mo < 4; ++mo)
        acc2[mo][cj] = __builtin_amdgcn_mfma_f32_16x16x32_bf16(af2[mo], bf, acc2[mo][cj], 0, 0, 0);
    }
  }

  // epilogue: + bias + fp32 residual, relu, store
#pragma unroll
  for (int mo = 0; mo < 4; ++mo)
#pragma unroll
    for (int cj = 0; cj < 2; ++cj) {
      int nl = wv * 32 + cj * 16 + l16;
      int n = nt * BN + nl;
#pragma unroll
      for (int r = 0; r < 4; ++r) {
        int o = mo * 16 + lg * 4 + r;
        size_t oi = (((size_t)bb * C_DIM + o) * T_DIM + tti) * N_DIM + n;
        float v = acc2[mo][cj][r] + bias[o] + x[oi];
        out[oi] = v > 0.f ? v : 0.f;
      }
    }
}

extern "C" void kernel_launch(void* const* d_in, const int* in_sizes, int n_in,
                              void* d_out, int out_size, void* d_ws, size_t ws_size,
                              hipStream_t stream) {
  (void)in_sizes; (void)n_in; (void)out_size; (void)ws_size;
  const float* x     = (const float*)d_in[0];
  const float* Lk    = (const float*)d_in[1];
  const float* theta = (const float*)d_in[2];
  const float* bias  = (const float*)d_in[3];
  float* out = (float*)d_out;

  u16* Lkb = (u16*)d_ws;                                              // 6 MB
  u16* thT = (u16*)((char*)d_ws + (size_t)KS_DIM * N_DIM * N_DIM * 2); // 24 KB

  k_convert_lk<<<KS_DIM * N_DIM * N_DIM / 8 / 256, 256, 0, stream>>>(Lk, Lkb);
  k_convert_theta<<<(C_DIM * C_DIM * KS_DIM + 255) / 256, 256, 0, stream>>>(theta, thT);
  k_main<<<B_DIM * T_DIM * (N_DIM / BN), 256, 0, stream>>>(x, Lkb, thT, bias, out);
}

// Round 3
// 1011.396 us; speedup vs baseline: 1.0080x; 1.0080x over previous
//
#include <hip/hip_runtime.h>
#include <cstdint>
#include <cstddef>

typedef unsigned short u16;
typedef __attribute__((ext_vector_type(8))) short short8;
typedef __attribute__((ext_vector_type(4))) float f32x4;

#define B_DIM 16
#define C_DIM 64
#define T_DIM 64
#define N_DIM 1024
#define KS_DIM 3

#define BN 128                    // n columns per workgroup
#define BK 32                     // K (m) step
#define NSTEP (N_DIM / BK)        // 32

__device__ __forceinline__ u16 f2bf(float f) {
  union { float f; uint32_t u; } v; v.f = f;
  uint32_t r = (v.u + 0x7FFFu + ((v.u >> 16) & 1u)) >> 16;  // RNE
  return (u16)r;
}

__device__ __forceinline__ void gload_lds16(const void* g, void* l) {
  __builtin_amdgcn_global_load_lds(
      (const __attribute__((address_space(1))) void*)g,
      (__attribute__((address_space(3))) void*)l, 16, 0, 0);
}

// ws kernel 1: Lk fp32 -> bf16 (natural [k][n][m] layout = B^T rows over m)
__global__ void k_convert_lk(const float* __restrict__ Lk, u16* __restrict__ Lkb) {
  size_t idx = (size_t)blockIdx.x * blockDim.x + threadIdx.x;  // one per 8 elems
  const float4* s = (const float4*)(Lk + idx * 8);
  float4 f0 = s[0], f1 = s[1];
  short8 h;
  h[0] = (short)f2bf(f0.x); h[1] = (short)f2bf(f0.y);
  h[2] = (short)f2bf(f0.z); h[3] = (short)f2bf(f0.w);
  h[4] = (short)f2bf(f1.x); h[5] = (short)f2bf(f1.y);
  h[6] = (short)f2bf(f1.z); h[7] = (short)f2bf(f1.w);
  *(short8*)(Lkb + idx * 8) = h;
}

// ws kernel 2: theta[i][o][k] -> thT[o][k*64+i] bf16 (A-operand for mix GEMM)
__global__ void k_convert_theta(const float* __restrict__ th, u16* __restrict__ thT) {
  int f = blockIdx.x * blockDim.x + threadIdx.x;
  if (f < C_DIM * C_DIM * KS_DIM) {
    int o = f / 192, ik = f % 192, k = ik >> 6, i = ik & 63;
    thT[f] = f2bf(th[(i * 64 + o) * 3 + k]);
  }
}

// Fused: z-GEMM (M=64 i, N=384 (k,n), K=1024 m) -> LDS transpose -> theta-mix
// MFMA (M=64 o, N=128 n, K=192 ik) -> bias + residual + relu.
// v2: B double-buffered + issue-early (loads fly under MFMA), A reg-staged,
//     XOR-swizzled LDS (16B-group ^= (row>>1)&3) on both write/source and read.
__global__ __launch_bounds__(256, 3)
void k_main(const float* __restrict__ x, const u16* __restrict__ Lkb,
            const u16* __restrict__ thT, const float* __restrict__ bias,
            float* __restrict__ out) {
  __shared__ __align__(16) char smem[53248];
  u16* Bb0 = (u16*)smem;              // 24 KB
  u16* Bb1 = (u16*)(smem + 24576);    // 24 KB
  u16* Ab  = (u16*)(smem + 49152);    // 4 KB  [64][32] swizzled
  char* Zb = smem;                    // phase 2: zT [128][200] bf16 (50 KB)

  const int tid = threadIdx.x;
  const int wv = tid >> 6;
  const int ln = tid & 63;
  const int lg = ln >> 4;
  const int l16 = ln & 15;

  const int bid = blockIdx.x;
  const int nt = bid & 7;           // n-tile fast: 8 WGs share one x slice
  const int slice = bid >> 3;
  const int bb = slice >> 6;
  const int tti = slice & 63;

  const f32x4 vzero = {0.f, 0.f, 0.f, 0.f};
  f32x4 acc[4][6];
#pragma unroll
  for (int a = 0; a < 4; ++a)
#pragma unroll
    for (int c = 0; c < 6; ++c) acc[a][c] = vzero;

  // ---- A staging geometry (one 16B chunk = 8 bf16 per thread) ----
  const int arow = tid >> 2, am = tid & 3;
  const float* a_src = x + (((size_t)bb * C_DIM + arow) * T_DIM + tti) * N_DIM + am * 8;
  // swizzled A destination (constant per thread)
  u16* a_dst = Ab + arow * BK + ((am ^ ((arow >> 1) & 3)) << 3);

  // ---- B staging geometry: hoist per-it source bases (swizzle baked in) ----
  const u16* b_srcb[6];
  char* b_dst_off[6];
#pragma unroll
  for (int it = 0; it < 6; ++it) {
    int L = it * 256 + tid;              // 0..1535 (16B chunks)
    int brow = L >> 2, msub = L & 3;
    int k = brow >> 7, nl = brow & 127;
    int msw = msub ^ ((brow >> 1) & 3);  // pre-swizzled global source group
    b_srcb[it] = Lkb + ((size_t)(k * N_DIM + nt * BN + nl)) * N_DIM + (msw << 3);
    b_dst_off[it] = (char*)((size_t)(it * 256 + wv * 64) * 16);  // wave-uniform
  }

  // ---- prologue: stage step 0 ----
  float4 a0 = *(const float4*)(a_src);
  float4 a1 = *(const float4*)(a_src + 4);
#pragma unroll
  for (int it = 0; it < 6; ++it)
    gload_lds16(b_srcb[it], (char*)Bb0 + (size_t)b_dst_off[it]);
  {
    short8 h;
    h[0] = (short)f2bf(a0.x); h[1] = (short)f2bf(a0.y);
    h[2] = (short)f2bf(a0.z); h[3] = (short)f2bf(a0.w);
    h[4] = (short)f2bf(a1.x); h[5] = (short)f2bf(a1.y);
    h[6] = (short)f2bf(a1.z); h[7] = (short)f2bf(a1.w);
    *(short8*)a_dst = h;
  }
  __syncthreads();   // compiler drains vmcnt+lgkm here: A(0), B(0) ready

  for (int kk = 0; kk < NSTEP; ++kk) {
    u16* Bcur = (kk & 1) ? Bb1 : Bb0;
    u16* Bnxt = (kk & 1) ? Bb0 : Bb1;
    // 1) issue next-step loads (fly under the MFMAs below)
    if (kk + 1 < NSTEP) {
#pragma unroll
      for (int it = 0; it < 6; ++it)
        gload_lds16(b_srcb[it] + (kk + 1) * BK, (char*)Bnxt + (size_t)b_dst_off[it]);
      a0 = *(const float4*)(a_src + (kk + 1) * BK);
      a1 = *(const float4*)(a_src + (kk + 1) * BK + 4);
    }
    // 2) compute step kk from Bcur/Ab (swizzled reads, conflict-free)
    short8 af[4];
#pragma unroll
    for (int mi = 0; mi < 4; ++mi) {
      int row = mi * 16 + l16;
      af[mi] = *(const short8*)(Ab + row * BK + ((lg ^ ((row >> 1) & 3)) << 3));
    }
#pragma unroll
    for (int ci = 0; ci < 6; ++ci) {
      int r = wv * 96 + ci * 16 + l16;
      short8 bfr = *(const short8*)(Bcur + r * BK + ((lg ^ ((r >> 1) & 3)) << 3));
#pragma unroll
      for (int mi = 0; mi < 4; ++mi)
        acc[mi][ci] = __builtin_amdgcn_mfma_f32_16x16x32_bf16(af[mi], bfr, acc[mi][ci], 0, 0, 0);
    }
    // 3) all waves done reading Ab -> safe to overwrite
    __syncthreads();
    if (kk + 1 < NSTEP) {
      short8 h;
      h[0] = (short)f2bf(a0.x); h[1] = (short)f2bf(a0.y);
      h[2] = (short)f2bf(a0.z); h[3] = (short)f2bf(a0.w);
      h[4] = (short)f2bf(a1.x); h[5] = (short)f2bf(a1.y);
      h[6] = (short)f2bf(a1.z); h[7] = (short)f2bf(a1.w);
      *(short8*)a_dst = h;
    }
    // 4) A written, B(k+1) drained (compiler vmcnt before barrier)
    __syncthreads();
  }

  // transpose z into LDS: zT[nl][k*64+i] (row padded to 200 bf16)
#pragma unroll
  for (int mi = 0; mi < 4; ++mi)
#pragma unroll
    for (int ci = 0; ci < 6; ++ci) {
      int c = wv * 96 + ci * 16 + l16;        // (k,nl) col of z
      int k = c >> 7, nl = c & 127;
      int ib = mi * 16 + lg * 4;              // i of reg 0
      uint32_t p0 = (uint32_t)f2bf(acc[mi][ci][0]) | ((uint32_t)f2bf(acc[mi][ci][1]) << 16);
      uint32_t p1 = (uint32_t)f2bf(acc[mi][ci][2]) | ((uint32_t)f2bf(acc[mi][ci][3]) << 16);
      *(uint32_t*)(Zb + ((size_t)nl * 200 + k * 64 + ib) * 2) = p0;
      *(uint32_t*)(Zb + ((size_t)nl * 200 + k * 64 + ib + 2) * 2) = p1;
    }
  __syncthreads();

  // mix GEMM: out[o][n] = sum_ik thT[o][ik] * zT[n][ik]
  f32x4 acc2[4][2];
#pragma unroll
  for (int a = 0; a < 4; ++a)
#pragma unroll
    for (int c = 0; c < 2; ++c) acc2[a][c] = vzero;

#pragma unroll
  for (int ks = 0; ks < 6; ++ks) {
    short8 af2[4];
#pragma unroll
    for (int mo = 0; mo < 4; ++mo) {
      int o = mo * 16 + l16;
      af2[mo] = *(const short8*)(thT + o * 192 + ks * 32 + lg * 8);  // L2-hot
    }
#pragma unroll
    for (int cj = 0; cj < 2; ++cj) {
      int nl = wv * 32 + cj * 16 + l16;
      short8 bfr = *(const short8*)(Zb + ((size_t)nl * 200 + ks * 32 + lg * 8) * 2);
#pragma unroll
      for (int mo = 0; mo < 4; ++mo)
        acc2[mo][cj] = __builtin_amdgcn_mfma_f32_16x16x32_bf16(af2[mo], bfr, acc2[mo][cj], 0, 0, 0);
    }
  }

  // epilogue: + bias + fp32 residual, relu, store
#pragma unroll
  for (int mo = 0; mo < 4; ++mo)
#pragma unroll
    for (int cj = 0; cj < 2; ++cj) {
      int nl = wv * 32 + cj * 16 + l16;
      int n = nt * BN + nl;
#pragma unroll
      for (int r = 0; r < 4; ++r) {
        int o = mo * 16 + lg * 4 + r;
        size_t oi = (((size_t)bb * C_DIM + o) * T_DIM + tti) * N_DIM + n;
        float v = acc2[mo][cj][r] + bias[o] + x[oi];
        out[oi] = v > 0.f ? v : 0.f;
      }
    }
}

extern "C" void kernel_launch(void* const* d_in, const int* in_sizes, int n_in,
                              void* d_out, int out_size, void* d_ws, size_t ws_size,
                              hipStream_t stream) {
  (void)in_sizes; (void)n_in; (void)out_size; (void)ws_size;
  const float* x     = (const float*)d_in[0];
  const float* Lk    = (const float*)d_in[1];
  const float* theta = (const float*)d_in[2];
  const float* bias  = (const float*)d_in[3];
  float* out = (float*)d_out;

  u16* Lkb = (u16*)d_ws;                                              // 6 MB
  u16* thT = (u16*)((char*)d_ws + (size_t)KS_DIM * N_DIM * N_DIM * 2); // 24 KB

  k_convert_lk<<<KS_DIM * N_DIM * N_DIM / 8 / 256, 256, 0, stream>>>(Lk, Lkb);
  k_convert_theta<<<(C_DIM * C_DIM * KS_DIM + 255) / 256, 256, 0, stream>>>(theta, thT);
  k_main<<<B_DIM * T_DIM * (N_DIM / BN), 256, 0, stream>>>(x, Lkb, thT, bias, out);
}